// Round 7
// baseline (692.477 us; speedup 1.0000x reference)
//
#include <hip/hip_runtime.h>
#include <stdint.h>

// W4A16 grouped-quant linear on MI355X (harness promotes fp16 -> f32):
// x f32[4096,4096], qweight i32[11008,2048] (2 nibbles in the LOW BYTE of
// each int32), scale f32[11008,32], zero i32[11008,32], bias f32[11008],
// out f32[4096,11008].
//
// Round 7: prep packs W to TRUE 4-bit (22.5 MB, L2-resident) + fused
// (scale,zero) u32 array; GEMM keeps the 256^2 8-phase schedule with A via
// global_load_lds and B dequantized in-loop (reg->LDS, exact fp16 math).
#define MDIM 4096
#define NDIM 11008
#define KDIM 4096
#define KHALF 2048   // int32 per qweight row
#define KBYTES 2048  // packed bytes per row (2 nibbles/byte)
#define NGRP 32
#define NXCD 8

#define XBYTES ((size_t)MDIM * KDIM * 2)     // 33.5 MB fp16 x
#define WPBYTES ((size_t)NDIM * KBYTES)      // 22.5 MB packed nibbles
#define SZBYTES ((size_t)NDIM * NGRP * 4)    // 1.4 MB fused scale/zero
#define WS_NEED (XBYTES + WPBYTES + SZBYTES)

// 8-phase GEMM geometry
#define G_BM 256
#define G_BN 256
#define G_NTH 512
#define G_NTILN (NDIM / G_BN)            // 43
#define G_NWG ((MDIM / G_BM) * G_NTILN)  // 688, divisible by 8

// fallback geometry (round-3 kernel)
#define F_BM 128
#define F_BN 128
#define F_BK 64
#define F_NTH 256
#define F_NTILN (NDIM / F_BN)
#define F_NWG ((MDIM / F_BM) * F_NTILN)

typedef __attribute__((ext_vector_type(4))) float f32x4;
typedef __attribute__((ext_vector_type(8))) _Float16 f16x8;
typedef __attribute__((ext_vector_type(2))) _Float16 h2;
typedef __attribute__((ext_vector_type(4))) int i32x4;
typedef __attribute__((ext_vector_type(4))) unsigned int u32x4;

__device__ __forceinline__ unsigned int pk16(float a, float b) {
  return __builtin_bit_cast(unsigned int, __builtin_amdgcn_cvt_pkrtz(a, b));
}
// round-3 fallback dequant (f32 path)
__device__ __forceinline__ unsigned int dq_pair(int qi, float fz, float s) {
  unsigned int q = (unsigned int)qi;
  float f0 = __uint_as_float((q & 0xFu) | 0x4B000000u);
  float f1 = __uint_as_float(((q >> 4) & 0xFu) | 0x4B000000u);
  return pk16((f0 - fz) * s, (f1 - fz) * s);
}
// Exact fp16 dequant of one packed byte (2 nibbles) -> 2 fp16.
// (1024+q) and (1024+z) are exact fp16; their difference q-z is exact;
// one packed fp16 multiply by s == the reference's fp16 math bit-for-bit.
__device__ __forceinline__ unsigned int dq_byte(unsigned int w, int bi,
                                                unsigned int zpk,
                                                unsigned int spk) {
  const unsigned int b = (w >> (8 * bi)) & 0xFFu;
  const unsigned int u = 0x64006400u | (b & 0xFu) | ((b & 0xF0u) << 12);
  const h2 r = (__builtin_bit_cast(h2, u) - __builtin_bit_cast(h2, zpk)) *
               __builtin_bit_cast(h2, spk);
  return __builtin_bit_cast(unsigned int, r);
}
__device__ __forceinline__ void load_lds16(const void* g, void* l) {
  __builtin_amdgcn_global_load_lds(
      (__attribute__((address_space(1))) void*)(void*)g,
      (__attribute__((address_space(3))) void*)l, 16, 0, 0);
}

// ---------------- prep 1: repack W4 (1 useful byte/int32) -> true 4-bit ----
__global__ void __launch_bounds__(256)
pack_w(const int* __restrict__ qw, unsigned char* __restrict__ wp) {
  const unsigned int TOT = (unsigned int)NDIM * KHALF / 16u;  // 16 int32/thr
  const unsigned int stride = gridDim.x * blockDim.x;
  for (unsigned int t = blockIdx.x * blockDim.x + threadIdx.x; t < TOT;
       t += stride) {
    const i32x4* qp = (const i32x4*)(qw + (size_t)t * 16);
    u32x4 o;
#pragma unroll
    for (int j = 0; j < 4; ++j) {
      const i32x4 q = qp[j];
      o[j] = ((unsigned)q[0] & 0xFFu) | (((unsigned)q[1] & 0xFFu) << 8) |
             (((unsigned)q[2] & 0xFFu) << 16) | (((unsigned)q[3] & 0xFFu) << 24);
    }
    *(u32x4*)(wp + (size_t)t * 16) = o;
  }
}

// ---------------- prep 2: x f32 -> fp16 (exact) ----------------
__global__ void __launch_bounds__(256)
cvt_x(const float* __restrict__ x, _Float16* __restrict__ xh) {
  const unsigned int XTOT = (unsigned int)MDIM * KDIM;
  const unsigned int stride = gridDim.x * blockDim.x;
  for (unsigned int t = blockIdx.x * blockDim.x + threadIdx.x; t * 8u < XTOT;
       t += stride) {
    const unsigned int f = t * 8u;
    const f32x4 a = *(const f32x4*)(x + f);
    const f32x4 b = *(const f32x4*)(x + f + 4);
    u32x4 w;
    w[0] = pk16(a[0], a[1]);
    w[1] = pk16(a[2], a[3]);
    w[2] = pk16(b[0], b[1]);
    w[3] = pk16(b[2], b[3]);
    *(u32x4*)(xh + f) = w;
  }
}

// ---------------- prep 3: fuse (scale,zero) -> u32 = f16(s) | z<<16 -------
__global__ void __launch_bounds__(256)
pack_sz(const float* __restrict__ scl, const int* __restrict__ zro,
        unsigned int* __restrict__ szp) {
  const unsigned int TOT = (unsigned int)NDIM * NGRP / 4u;
  const unsigned int stride = gridDim.x * blockDim.x;
  for (unsigned int t = blockIdx.x * blockDim.x + threadIdx.x; t < TOT;
       t += stride) {
    const f32x4 s = *(const f32x4*)(scl + (size_t)t * 4);
    const i32x4 z = *(const i32x4*)(zro + (size_t)t * 4);
    u32x4 o;
#pragma unroll
    for (int j = 0; j < 4; ++j) {
      const unsigned int sb = pk16(s[j], s[j]) & 0xFFFFu;  // exact (s was fp16)
      o[j] = sb | ((unsigned)z[j] << 16);
    }
    *(u32x4*)(szp + (size_t)t * 4) = o;
  }
}

// ---------------- GEMM: 256^2 8-phase, A gload_lds + B in-loop dequant ----
#define ABUF(b, h) ((b) * 32768 + (h) * 8192)
#define BBUF(b, h) ((b) * 32768 + 16384 + (h) * 8192)

#define BARRIER __builtin_amdgcn_s_barrier()
#define LGK0 do { asm volatile("s_waitcnt lgkmcnt(0)" ::: "memory"); \
                  __builtin_amdgcn_sched_barrier(0); } while (0)
#define VMC(N) do { asm volatile("s_waitcnt vmcnt(" #N ")" ::: "memory"); \
                    __builtin_amdgcn_sched_barrier(0); } while (0)
#define FENCE do { asm volatile("" ::: "memory"); \
                   __builtin_amdgcn_sched_barrier(0); } while (0)

__global__ void __launch_bounds__(G_NTH, 2)
gemm_w4(const _Float16* __restrict__ xh, const unsigned char* __restrict__ wp,
        const unsigned int* __restrict__ szp, const float* __restrict__ bia,
        float* __restrict__ outp) {
  __shared__ _Float16 lds[65536];  // 128 KiB

  const int tid = threadIdx.x;
  int wg = blockIdx.x;  // bijective XCD swizzle (688 = 8*86)
  wg = (wg & 7) * (G_NWG / 8) + (wg >> 3);
  const int by = wg / G_NTILN;
  const int bx = wg - by * G_NTILN;
  const int m0 = by * G_BM;
  const int n0 = bx * G_BN;

  // A staging (gload_lds): rows via tid>>3, pre-swizzled source column
  const int rowL = tid >> 3;
  const int swc = (((tid & 7) ^ (rowL & 7)) << 3);
  const unsigned int aO0 = (unsigned int)(m0 + rowL) * KDIM + swc;
  const unsigned int aO1 = aO0 + (unsigned int)128 * KDIM;
  const int dst0 = tid << 3;

#define ST(base_el, gb, thoff, ko)                                     \
  do {                                                                 \
    load_lds16((gb) + (thoff) + (ko), lds + (base_el) + dst0);         \
    load_lds16((gb) + (thoff) + (unsigned)64 * KDIM + (ko),            \
               lds + (base_el) + 4096 + dst0);                         \
  } while (0)

  // B staging (reg dequant): thread = (row nloc, k-half bh), 16 B -> 32 fp16
  const int nloc = tid >> 1;
  const int bh = tid & 1;
  const int nsw = nloc & 7;
  const unsigned char* bqp = wp + (size_t)(n0 + nloc) * KBYTES + bh * 16;
  const unsigned int* szr = szp + (size_t)(n0 + nloc) * NGRP;

#define DQW(QV, BUF)                                                      \
  do {                                                                    \
    _Pragma("unroll") for (int j = 0; j < 4; ++j) {                       \
      u32x4 o;                                                            \
      _Pragma("unroll") for (int bi = 0; bi < 4; ++bi)                    \
        o[bi] = dq_byte((QV)[j], bi, zpk, spk);                           \
      *(u32x4*)(lds + (BUF) * 32768 + 16384 + nloc * 64 +                 \
                ((((bh << 2) + j) ^ nsw) << 3)) = o;                      \
    }                                                                     \
  } while (0)

  // wave decomposition: 2M x 4N waves; per-wave C = 128x64
  const int wave = tid >> 6, lane = tid & 63;
  const int wm = wave >> 2, wn = wave & 3;
  const int fr = lane & 15, fq = lane >> 4;
  const int pc0 = (fq ^ (fr & 7)) << 3;
  const int pc1 = ((4 + fq) ^ (fr & 7)) << 3;
  const int aoff0 = fr * 64 + pc0, aoff1 = fr * 64 + pc1;
  const int bb = ((wn & 1) << 12) + fr * 64;
  const int boff0 = bb + pc0, boff1 = bb + pc1;

  const _Float16* aP0 = lds + ABUF(0, 0) + wm * 8192;
  const _Float16* aP1 = lds + ABUF(1, 0) + wm * 8192;
  const _Float16* bP0 = lds + BBUF(0, 0) + (wn >> 1) * 8192;
  const _Float16* bP1 = lds + BBUF(1, 0) + (wn >> 1) * 8192;

#define RD_A03(P)                                           \
  _Pragma("unroll") for (int u = 0; u < 4; ++u) {           \
    aF[u][0] = *(const f16x8*)((P) + u * 1024 + aoff0);     \
    aF[u][1] = *(const f16x8*)((P) + u * 1024 + aoff1);     \
  }
#define RD_A47(P)                                                 \
  _Pragma("unroll") for (int u = 0; u < 4; ++u) {                 \
    aF[4 + u][0] = *(const f16x8*)((P) + (4 + u) * 1024 + aoff0); \
    aF[4 + u][1] = *(const f16x8*)((P) + (4 + u) * 1024 + aoff1); \
  }
#define RD_B01(P)                                           \
  _Pragma("unroll") for (int v = 0; v < 2; ++v) {           \
    bF[v][0] = *(const f16x8*)((P) + v * 1024 + boff0);     \
    bF[v][1] = *(const f16x8*)((P) + v * 1024 + boff1);     \
  }
#define RD_B23(P)                                                 \
  _Pragma("unroll") for (int v = 0; v < 2; ++v) {                 \
    bF[2 + v][0] = *(const f16x8*)((P) + (2 + v) * 1024 + boff0); \
    bF[2 + v][1] = *(const f16x8*)((P) + (2 + v) * 1024 + boff1); \
  }
#define QUAD(MI, NI)                                                     \
  do {                                                                   \
    __builtin_amdgcn_s_setprio(1);                                       \
    _Pragma("unroll") for (int u = 0; u < 4; ++u) {                      \
      _Pragma("unroll") for (int v = 0; v < 2; ++v) {                    \
        acc[(MI) + u][(NI) + v] = __builtin_amdgcn_mfma_f32_16x16x32_f16( \
            aF[(MI) + u][0], bF[(NI) + v][0], acc[(MI) + u][(NI) + v], 0, 0, 0); \
        acc[(MI) + u][(NI) + v] = __builtin_amdgcn_mfma_f32_16x16x32_f16( \
            aF[(MI) + u][1], bF[(NI) + v][1], acc[(MI) + u][(NI) + v], 0, 0, 0); \
      }                                                                  \
    }                                                                    \
    __builtin_amdgcn_s_setprio(0);                                       \
  } while (0)

  f16x8 aF[8][2], bF[4][2];
  f32x4 acc[8][4];
  const f32x4 fzero = {0.f, 0.f, 0.f, 0.f};
#pragma unroll
  for (int i = 0; i < 8; ++i)
#pragma unroll
    for (int j = 0; j < 4; ++j) acc[i][j] = fzero;

  unsigned int zpk = 0, spk = 0;

  // ---- prologue: B bytes t0,t1 + sz(g0) -> regs; A tiles 0,1 -> LDS ----
  u32x4 q0 = *(const u32x4*)(bqp + 0);
  u32x4 q1 = *(const u32x4*)(bqp + 32);
  unsigned int szv = szr[0];
  FENCE;
  ST(ABUF(0, 0), xh, aO0, 0u);
  ST(ABUF(0, 1), xh, aO1, 0u);
  ST(ABUF(1, 0), xh, aO0, 64u);
  ST(ABUF(1, 1), xh, aO1, 64u);
  FENCE;
  VMC(8);  // retire q0,q1,szv (oldest 3 of 11)
  {
    const unsigned int zl = szv >> 16;
    zpk = 0x64006400u | zl | (zl << 16);
    spk = (szv & 0xFFFFu) | (szv << 16);
    DQW(q0, 0);
    DQW(q1, 1);
  }
  VMC(4);  // ABUF(0,*) complete; ABUF(1,*) 4 loads stay in flight
  LGK0;    // drain dequant ds_writes
  BARRIER;

  for (int it = 0; it < KDIM / 128; ++it) {
    const unsigned int ko2 = (128u * it + 128u) & 4095u;  // A el, tile t0+2
    const unsigned int ko3 = (128u * it + 192u) & 4095u;  // A el, tile t1+2
    const unsigned int kb2 = (64u * it + 64u) & 2047u;    // B bytes, t0+2
    const unsigned int kb3 = (64u * it + 96u) & 2047u;    // B bytes, t1+2

    // ph1
    RD_A03(aP0); RD_B01(bP0);
    q0 = *(const u32x4*)(bqp + kb2);
    szv = szr[(it + 1) & 31];
    BARRIER; LGK0; QUAD(0, 0); BARRIER;
    // ph2
    RD_A47(aP0);
    BARRIER; LGK0; QUAD(4, 0); BARRIER;
    // ph3
    RD_B23(bP0);
    ST(ABUF(0, 0), xh, aO0, ko2);
    BARRIER; LGK0; QUAD(0, 2); BARRIER;
    // ph4: retire {prev A(4), q0, szv}; dequant -> BBUF(0)
    VMC(2);
    {
      const unsigned int zl = szv >> 16;
      zpk = 0x64006400u | zl | (zl << 16);
      spk = (szv & 0xFFFFu) | (szv << 16);
      DQW(q0, 0);
    }
    ST(ABUF(0, 1), xh, aO1, ko2);
    BARRIER; LGK0; QUAD(4, 2); BARRIER;
    // ph5
    RD_A03(aP1); RD_B01(bP1);
    q1 = *(const u32x4*)(bqp + kb3);
    BARRIER; LGK0; QUAD(0, 0); BARRIER;
    // ph6
    RD_A47(aP1);
    BARRIER; LGK0; QUAD(4, 0); BARRIER;
    // ph7
    RD_B23(bP1);
    ST(ABUF(1, 0), xh, aO0, ko3);
    BARRIER; LGK0; QUAD(0, 2); BARRIER;
    // ph8: retire {ph3/ph4 A(4), q1}; dequant -> BBUF(1)
    VMC(2);
    DQW(q1, 1);  // same group -> reuse zpk/spk
    ST(ABUF(1, 1), xh, aO1, ko3);
    BARRIER; LGK0; QUAD(4, 2); BARRIER;
  }

  // epilogue: C/D col(n) = fr, row(m) = fq*4 + j
#pragma unroll
  for (int ni = 0; ni < 4; ++ni) {
    const int n = n0 + wn * 64 + ni * 16 + fr;
    const float bv = bia[n];
#pragma unroll
    for (int mi = 0; mi < 8; ++mi) {
      const int m = m0 + wm * 128 + mi * 16 + (fq << 2);
      const size_t base = (size_t)m * NDIM + n;
#pragma unroll
      for (int j = 0; j < 4; ++j)
        outp[base + (size_t)j * NDIM] = acc[mi][ni][j] + bv;
    }
  }
}

// ---------------- fallback: round-3 fused kernel ----------------
__global__ void __launch_bounds__(F_NTH)
wlinear_fused(const float* __restrict__ x, const int* __restrict__ qw,
              const float* __restrict__ scl, const int* __restrict__ zro,
              const float* __restrict__ bia, float* __restrict__ outp) {
  __shared__ _Float16 ldsA[F_BM][F_BK];
  __shared__ _Float16 ldsB[F_BN][F_BK];

  const int tid = threadIdx.x;
  int wg = blockIdx.x;
  wg = (wg & (NXCD - 1)) * (F_NWG / NXCD) + (wg >> 3);
  const int by = wg / F_NTILN;
  const int bx = wg - by * F_NTILN;
  const int m0 = by * F_BM;
  const int n0 = bx * F_BN;

  const int srow = tid >> 1;
  const int sh = tid & 1;
  const int ssw = srow & 7;
  const float* xrow = x + (size_t)(m0 + srow) * KDIM + sh * 32;
  const int* qrow = qw + (size_t)(n0 + srow) * KHALF + sh * 16;
  const float* sclrow = scl + (size_t)(n0 + srow) * NGRP;
  const int* zrow = zro + (size_t)(n0 + srow) * NGRP;

  const int wave = tid >> 6;
  const int lane = tid & 63;
  const int wr = wave >> 1;
  const int wc = wave & 1;
  const int fr = lane & 15;
  const int fq = lane >> 4;
  const int off0 = ((fq ^ (fr & 7)) << 3);

  const f32x4 fzero = {0.f, 0.f, 0.f, 0.f};
  f32x4 acc[4][4];
#pragma unroll
  for (int i = 0; i < 4; ++i)
#pragma unroll
    for (int j = 0; j < 4; ++j) acc[i][j] = fzero;

  f32x4 xv[8];
  i32x4 qv[4];
  {
    const f32x4* xp = (const f32x4*)xrow;
#pragma unroll
    for (int i = 0; i < 8; ++i) xv[i] = xp[i];
    const i32x4* qp = (const i32x4*)qrow;
#pragma unroll
    for (int i = 0; i < 4; ++i) qv[i] = qp[i];
  }
  float s_n = sclrow[0];
  float fz_n = __uint_as_float(0x4B000000u | (unsigned int)zrow[0]);

  for (int k0 = 0; k0 < KDIM; k0 += F_BK) {
    __syncthreads();
#pragma unroll
    for (int j = 0; j < 4; ++j) {
      u32x4 wch;
      wch[0] = pk16(xv[2 * j][0], xv[2 * j][1]);
      wch[1] = pk16(xv[2 * j][2], xv[2 * j][3]);
      wch[2] = pk16(xv[2 * j + 1][0], xv[2 * j + 1][1]);
      wch[3] = pk16(xv[2 * j + 1][2], xv[2 * j + 1][3]);
      const int ps = (sh * 4 + j) ^ ssw;
      *(u32x4*)&ldsA[srow][ps << 3] = wch;
    }
#pragma unroll
    for (int ii = 0; ii < 4; ++ii) {
      u32x4 wch;
#pragma unroll
      for (int e = 0; e < 4; ++e) wch[e] = dq_pair(qv[ii][e], fz_n, s_n);
      const int ps = (sh * 4 + ii) ^ ssw;
      *(u32x4*)&ldsB[srow][ps << 3] = wch;
    }
    if (k0 + F_BK < KDIM) {
      const f32x4* xp = (const f32x4*)(xrow + k0 + F_BK);
#pragma unroll
      for (int i = 0; i < 8; ++i) xv[i] = xp[i];
      const i32x4* qp = (const i32x4*)(qrow + ((k0 + F_BK) >> 1));
#pragma unroll
      for (int i = 0; i < 4; ++i) qv[i] = qp[i];
      const int gn = (k0 + F_BK) >> 7;
      s_n = sclrow[gn];
      fz_n = __uint_as_float(0x4B000000u | (unsigned int)zrow[gn]);
    }
    __syncthreads();

#pragma unroll
    for (int ks = 0; ks < F_BK; ks += 32) {
      const int off = (ks == 0) ? off0 : (off0 ^ 32);
      f16x8 a[4], b[4];
#pragma unroll
      for (int mi = 0; mi < 4; ++mi)
        a[mi] = *(const f16x8*)&ldsA[wr * 64 + mi * 16 + fr][off];
#pragma unroll
      for (int ni = 0; ni < 4; ++ni)
        b[ni] = *(const f16x8*)&ldsB[wc * 64 + ni * 16 + fr][off];
#pragma unroll
      for (int mi = 0; mi < 4; ++mi)
#pragma unroll
        for (int ni = 0; ni < 4; ++ni)
          acc[mi][ni] = __builtin_amdgcn_mfma_f32_16x16x32_f16(
              a[mi], b[ni], acc[mi][ni], 0, 0, 0);
    }
  }

#pragma unroll
  for (int ni = 0; ni < 4; ++ni) {
    const int n = n0 + wc * 64 + ni * 16 + fr;
    const float bv = bia[n];
#pragma unroll
    for (int mi = 0; mi < 4; ++mi) {
      const int m = m0 + wr * 64 + mi * 16 + (fq << 2);
      const size_t base = (size_t)m * NDIM + n;
#pragma unroll
      for (int j = 0; j < 4; ++j)
        outp[base + (size_t)j * NDIM] = acc[mi][ni][j] + bv;
    }
  }
}

extern "C" void kernel_launch(void* const* d_in, const int* in_sizes, int n_in,
                              void* d_out, int out_size, void* d_ws, size_t ws_size,
                              hipStream_t stream) {
  (void)in_sizes; (void)n_in; (void)out_size;
  const float* x = (const float*)d_in[0];
  const int* qw = (const int*)d_in[1];
  const float* scl = (const float*)d_in[2];
  const int* zro = (const int*)d_in[3];
  const float* bia = (const float*)d_in[4];
  float* outp = (float*)d_out;

  if (ws_size >= WS_NEED) {
    _Float16* xh = (_Float16*)d_ws;
    unsigned char* wpk = (unsigned char*)d_ws + XBYTES;
    unsigned int* szp = (unsigned int*)((char*)d_ws + XBYTES + WPBYTES);
    cvt_x<<<1024, 256, 0, stream>>>(x, xh);
    pack_w<<<1024, 256, 0, stream>>>(qw, wpk);
    pack_sz<<<344, 256, 0, stream>>>(scl, zro, szp);
    gemm_w4<<<G_NWG, G_NTH, 0, stream>>>(xh, wpk, szp, bia, outp);
  } else {
    wlinear_fused<<<F_NWG, F_NTH, 0, stream>>>(x, qw, scl, zro, bia, outp);
  }
}